// Round 5
// baseline (32041.425 us; speedup 1.0000x reference)
//
#include <hip/hip_runtime.h>
#include <hip/hip_bf16.h>

// 2-layer LSTM, persistent kernel, BOTH layers fused per block.
// B=16, S=2048, I=256, H=512. 32 blocks x 512 threads (8 waves).
// Waves 0-3: layer0 gates (i,f,g,o) for 16 units; waves 4-7: layer1 gates.
// Superstep t: compute h0[t] (from h0[t-1], x[t]) AND h1[t-1] (from h0[t-1],
// h1[t-2]) -> ONE grid-wide handshake per superstep (wave-0-only polling,
// per-block cache-line-padded monotonic flags, relaxed agent atomics; no
// cache-wide fences anywhere).

#define BB 16
#define SS 2048
#define II 256
#define HH 512
#define NBLK 32
#define BHH (BB * HH)
#define OUT_H_OFF (BB * SS * HH)
#define OUT_C_OFF (OUT_H_OFF + 2 * BB * HH)

typedef __bf16 bf16x8_t __attribute__((ext_vector_type(8)));
typedef float f32x4_t __attribute__((ext_vector_type(4)));

union b128u { uint64_t u[2]; bf16x8_t v; };

__device__ __forceinline__ float sigmoidf_(float x) { return 1.f / (1.f + __expf(-x)); }
__device__ __forceinline__ float tanhf_(float x) { return 1.f - 2.f / (__expf(2.f * x) + 1.f); }

// agent-scope (LLC coherence point) accessors — bypass non-coherent L1/L2
__device__ __forceinline__ uint64_t cload64(const void* p) {
    return __hip_atomic_load((const uint64_t*)p, __ATOMIC_RELAXED, __HIP_MEMORY_SCOPE_AGENT);
}
__device__ __forceinline__ bf16x8_t cload_frag(const __bf16* p) {
    b128u r;
    r.u[0] = cload64(p);
    r.u[1] = cload64(p + 4);
    return r.v;
}
__device__ __forceinline__ void cstore_bf16(__bf16* p, float v) {
    __bf16 b = (__bf16)v;
    unsigned short u;
    __builtin_memcpy(&u, &b, 2);
    __hip_atomic_store((unsigned short*)p, u, __ATOMIC_RELAXED, __HIP_MEMORY_SCOPE_AGENT);
}

__device__ __forceinline__ bf16x8_t pack8(f32x4_t a, f32x4_t b) {
    bf16x8_t r;
    r[0] = (__bf16)a[0]; r[1] = (__bf16)a[1];
    r[2] = (__bf16)a[2]; r[3] = (__bf16)a[3];
    r[4] = (__bf16)b[0]; r[5] = (__bf16)b[1];
    r[6] = (__bf16)b[2]; r[7] = (__bf16)b[3];
    return r;
}
__device__ __forceinline__ bf16x8_t cvt8(const float* p) {
    return pack8(*reinterpret_cast<const f32x4_t*>(p),
                 *reinterpret_cast<const f32x4_t*>(p + 4));
}

#define MFMA(A, B, C) __builtin_amdgcn_mfma_f32_16x16x32_bf16((A), (B), (C), 0, 0, 0)

__global__ __launch_bounds__(512, 1) void lstm2_fused(
    const float* __restrict__ x,   // [B][S][I]
    const float* __restrict__ W0,  // [4H][I+H]
    const float* __restrict__ b0,  // [4H]
    const float* __restrict__ W1,  // [4H][2H]
    const float* __restrict__ b1,  // [4H]
    float* __restrict__ out,       // [B][S][H] then h[2][B][H], c[2][B][H]
    int* flags,                    // [NBLK*32]: block b's counter at flags[b*32]
    __bf16* h0buf, __bf16* h1buf)  // [2][B][H] parity double buffers
{
    const int tid  = threadIdx.x;
    const int w    = tid >> 6;   // wave 0..7
    const int l    = tid & 63;
    const int cc   = l & 15;     // B-frag col (gate unit) / A-frag row (batch)
    const int kg   = l >> 4;     // k-group 0..3
    const int gate = w & 3;
    const bool isL0 = (w < 4);
    const int blk   = blockIdx.x;
    const int ubase = blk * 16;
    const int gcol  = gate * HH + ubase + cc;

    // elementwise mapping: threads 0-255 -> layer0 cell, 256-511 -> layer1 cell
    const int half = tid >> 8;
    const int eb   = (tid >> 4) & 15;
    const int eu   = tid & 15;

    __shared__ float g0s[4][16][17];
    __shared__ float g1s[4][16][17];

    bf16x8_t wf[32];
    float    bias;
    bf16x8_t xf[8];
    const float* xrow = x + (size_t)cc * SS * II;  // batch cc

    if (isL0) {
        const float* wrow = W0 + (size_t)gcol * (II + HH);
#pragma unroll
        for (int kk = 0; kk < 24; ++kk)
            wf[kk] = cvt8(wrow + kk * 32 + kg * 8);
        bias = b0[gcol];
#pragma unroll
        for (int kk = 0; kk < 8; ++kk)                 // x[0] prologue
            xf[kk] = cvt8(xrow + kk * 32 + kg * 8);
    } else {
        const float* wrow = W1 + (size_t)gcol * (2 * HH);
#pragma unroll
        for (int kk = 0; kk < 32; ++kk)
            wf[kk] = cvt8(wrow + kk * 32 + kg * 8);
        bias = b1[gcol];
    }

    float cstate = 0.f;
    __syncthreads();

    for (int t = 0; t <= SS; ++t) {
        f32x4_t a0 = {0.f, 0.f, 0.f, 0.f}, a1 = a0, a2 = a0, a3 = a0;
        f32x4_t xraw[16];

        if (isL0 && t < SS) {
            // x-part: independent of peers — compute before the handshake
            a0 = MFMA(xf[0], wf[0], a0); a1 = MFMA(xf[1], wf[1], a1);
            a2 = MFMA(xf[2], wf[2], a2); a3 = MFMA(xf[3], wf[3], a3);
            a0 = MFMA(xf[4], wf[4], a0); a1 = MFMA(xf[5], wf[5], a1);
            a2 = MFMA(xf[6], wf[6], a2); a3 = MFMA(xf[7], wf[7], a3);
            if (t + 1 < SS) {
                // issue next-step x loads; latency hides under the spin
                const float* xr = xrow + (size_t)(t + 1) * II;
#pragma unroll
                for (int kk = 0; kk < 8; ++kk) {
                    xraw[2 * kk]     = *reinterpret_cast<const f32x4_t*>(xr + kk * 32 + kg * 8);
                    xraw[2 * kk + 1] = *reinterpret_cast<const f32x4_t*>(xr + kk * 32 + kg * 8 + 4);
                }
            }
        }

        // ---- single grid-wide handshake: all blocks completed superstep t-1
        if (w == 0) {
            const int* p = flags + (l & 31) * 32;   // one 128-B line per block
            while (true) {
                int v = __hip_atomic_load(p, __ATOMIC_RELAXED, __HIP_MEMORY_SCOPE_AGENT);
                if (__all(v >= t)) break;
            }
        }
        __syncthreads();

        if (isL0) {
            if (t < SS) {
                // pack next-step x first (loads drained during the spin) —
                // shortens xraw live range, cuts VGPR pressure in h-MFMA section
                if (t + 1 < SS) {
#pragma unroll
                    for (int kk = 0; kk < 8; ++kk)
                        xf[kk] = pack8(xraw[2 * kk], xraw[2 * kk + 1]);
                }
                if (t > 0) {
                    const __bf16* hp = h0buf + ((t - 1) & 1) * BHH + cc * HH + kg * 8;
#pragma unroll
                    for (int kk = 0; kk < 16; kk += 4) {
                        a0 = MFMA(cload_frag(hp + (kk + 0) * 32), wf[8 + kk + 0], a0);
                        a1 = MFMA(cload_frag(hp + (kk + 1) * 32), wf[8 + kk + 1], a1);
                        a2 = MFMA(cload_frag(hp + (kk + 2) * 32), wf[8 + kk + 2], a2);
                        a3 = MFMA(cload_frag(hp + (kk + 3) * 32), wf[8 + kk + 3], a3);
                    }
                }
                f32x4_t acc = (a0 + a1) + (a2 + a3);
#pragma unroll
                for (int r = 0; r < 4; ++r)
                    g0s[gate][cc][kg * 4 + r] = acc[r] + bias;
            }
        } else {
            if (t >= 1) {
                if (t >= 2) {
                    const __bf16* h1p = h1buf + ((t - 2) & 1) * BHH + cc * HH + kg * 8;
#pragma unroll
                    for (int kk = 0; kk < 16; kk += 4) {
                        a0 = MFMA(cload_frag(h1p + (kk + 0) * 32), wf[16 + kk + 0], a0);
                        a1 = MFMA(cload_frag(h1p + (kk + 1) * 32), wf[16 + kk + 1], a1);
                        a2 = MFMA(cload_frag(h1p + (kk + 2) * 32), wf[16 + kk + 2], a2);
                        a3 = MFMA(cload_frag(h1p + (kk + 3) * 32), wf[16 + kk + 3], a3);
                    }
                }
                const __bf16* h0c = h0buf + ((t - 1) & 1) * BHH + cc * HH + kg * 8;
#pragma unroll
                for (int kk = 0; kk < 16; kk += 4) {
                    a0 = MFMA(cload_frag(h0c + (kk + 0) * 32), wf[kk + 0], a0);
                    a1 = MFMA(cload_frag(h0c + (kk + 1) * 32), wf[kk + 1], a1);
                    a2 = MFMA(cload_frag(h0c + (kk + 2) * 32), wf[kk + 2], a2);
                    a3 = MFMA(cload_frag(h0c + (kk + 3) * 32), wf[kk + 3], a3);
                }
                f32x4_t acc = (a0 + a1) + (a2 + a3);
#pragma unroll
                for (int r = 0; r < 4; ++r)
                    g1s[gate][cc][kg * 4 + r] = acc[r] + bias;
            }
        }
        __syncthreads();

        if (half == 0) {
            if (t < SS) {
                const float gi = g0s[0][eu][eb];
                const float gf = g0s[1][eu][eb];
                const float gg = g0s[2][eu][eb];
                const float go = g0s[3][eu][eb];
                const float cn = sigmoidf_(gf) * cstate + sigmoidf_(gi) * tanhf_(gg);
                const float hn = sigmoidf_(go) * tanhf_(cn);
                cstate = cn;
                cstore_bf16(h0buf + (t & 1) * BHH + eb * HH + ubase + eu, hn);
                if (t == SS - 1) {
                    out[OUT_H_OFF + eb * HH + ubase + eu] = hn;
                    out[OUT_C_OFF + eb * HH + ubase + eu] = cn;
                }
            }
        } else {
            if (t >= 1) {
                const float gi = g1s[0][eu][eb];
                const float gf = g1s[1][eu][eb];
                const float gg = g1s[2][eu][eb];
                const float go = g1s[3][eu][eb];
                const float cn = sigmoidf_(gf) * cstate + sigmoidf_(gi) * tanhf_(gg);
                const float hn = sigmoidf_(go) * tanhf_(cn);
                cstate = cn;
                cstore_bf16(h1buf + ((t - 1) & 1) * BHH + eb * HH + ubase + eu, hn);
                out[((size_t)eb * SS + (t - 1)) * HH + ubase + eu] = hn;
                if (t == SS) {
                    out[OUT_H_OFF + (BB + eb) * HH + ubase + eu] = hn;
                    out[OUT_C_OFF + (BB + eb) * HH + ubase + eu] = cn;
                }
            }
        }

        asm volatile("s_waitcnt vmcnt(0)" ::: "memory");  // h stores at LLC
        __syncthreads();                                  // all waves drained
        if (tid == 0)
            __hip_atomic_store(flags + blk * 32, t + 1, __ATOMIC_RELAXED,
                               __HIP_MEMORY_SCOPE_AGENT);
    }
}

extern "C" void kernel_launch(void* const* d_in, const int* in_sizes, int n_in,
                              void* d_out, int out_size, void* d_ws, size_t ws_size,
                              hipStream_t stream) {
    const float* x  = (const float*)d_in[0];
    const float* W0 = (const float*)d_in[1];
    const float* b0 = (const float*)d_in[2];
    const float* W1 = (const float*)d_in[3];
    const float* b1 = (const float*)d_in[4];
    float* out = (float*)d_out;

    char* ws = (char*)d_ws;
    int* flags = (int*)ws;                          // NBLK * 32 ints (padded)
    __bf16* h0buf = (__bf16*)(ws + 8192);           // 2*B*H bf16 = 32 KB
    __bf16* h1buf = (__bf16*)(ws + 8192 + 32768);   // 2*B*H bf16 = 32 KB

    hipMemsetAsync(ws, 0, 8192, stream);  // zero flag counters

    hipLaunchKernelGGL(lstm2_fused, dim3(NBLK), dim3(512), 0, stream,
                       x, W0, b0, W1, b1, out, flags, h0buf, h1buf);
}

// Round 6
// 24843.935 us; speedup vs baseline: 1.2897x; 1.2897x over previous
//
#include <hip/hip_runtime.h>
#include <hip/hip_bf16.h>

// 2-layer LSTM, persistent kernel, both layers fused per block.
// B=16, S=2048, I=256, H=512. 32 blocks x 512 threads (8 waves).
// Waves 0-3: layer0 gates (i,f,g,o); waves 4-7: layer1 gates.
// ONE grid handshake per superstep (per-block line-padded monotonic flags).
// h-state crosses XCDs via PLAIN pipelined global_load_dwordx4 sc0 sc1
// (cache-bypassing, non-atomic -> 16 loads in flight, ONE LLC latency)
// + one s_waitcnt vmcnt(0) before the MFMA cluster.

#define BB 16
#define SS 2048
#define II 256
#define HH 512
#define NBLK 32
#define BHH (BB * HH)
#define OUT_H_OFF (BB * SS * HH)
#define OUT_C_OFF (OUT_H_OFF + 2 * BB * HH)

typedef __bf16 bf16x8_t __attribute__((ext_vector_type(8)));
typedef float f32x4_t __attribute__((ext_vector_type(4)));

__device__ __forceinline__ float sigmoidf_(float x) { return 1.f / (1.f + __expf(-x)); }
__device__ __forceinline__ float tanhf_(float x) { return 1.f - 2.f / (__expf(2.f * x) + 1.f); }

// plain cache-bypassing 16B load (coherence point), pipelined in VMEM queue.
// NOTE: dst NOT valid until s_waitcnt vmcnt; callers wait explicitly.
#define CLOAD(dst, base, BOFF)                                               \
    asm volatile("global_load_dwordx4 %0, %1, off offset:" #BOFF " sc0 sc1"  \
                 : "=v"(dst) : "v"(base))

__device__ __forceinline__ void cload_block16(bf16x8_t hf[16], const __bf16* hp) {
    CLOAD(hf[0],  hp, 0);   CLOAD(hf[1],  hp, 64);
    CLOAD(hf[2],  hp, 128); CLOAD(hf[3],  hp, 192);
    CLOAD(hf[4],  hp, 256); CLOAD(hf[5],  hp, 320);
    CLOAD(hf[6],  hp, 384); CLOAD(hf[7],  hp, 448);
    CLOAD(hf[8],  hp, 512); CLOAD(hf[9],  hp, 576);
    CLOAD(hf[10], hp, 640); CLOAD(hf[11], hp, 704);
    CLOAD(hf[12], hp, 768); CLOAD(hf[13], hp, 832);
    CLOAD(hf[14], hp, 896); CLOAD(hf[15], hp, 960);
}

#define WAIT_VMEM()                                   \
    do {                                              \
        asm volatile("s_waitcnt vmcnt(0)" ::: "memory"); \
        __builtin_amdgcn_sched_barrier(0);            \
    } while (0)

__device__ __forceinline__ void cstore_bf16(__bf16* p, float v) {
    __bf16 b = (__bf16)v;
    unsigned short u;
    __builtin_memcpy(&u, &b, 2);
    __hip_atomic_store((unsigned short*)p, u, __ATOMIC_RELAXED, __HIP_MEMORY_SCOPE_AGENT);
}

__device__ __forceinline__ bf16x8_t pack8(f32x4_t a, f32x4_t b) {
    bf16x8_t r;
    r[0] = (__bf16)a[0]; r[1] = (__bf16)a[1];
    r[2] = (__bf16)a[2]; r[3] = (__bf16)a[3];
    r[4] = (__bf16)b[0]; r[5] = (__bf16)b[1];
    r[6] = (__bf16)b[2]; r[7] = (__bf16)b[3];
    return r;
}
__device__ __forceinline__ bf16x8_t cvt8(const float* p) {
    return pack8(*reinterpret_cast<const f32x4_t*>(p),
                 *reinterpret_cast<const f32x4_t*>(p + 4));
}

#define MFMA(A, B, C) __builtin_amdgcn_mfma_f32_16x16x32_bf16((A), (B), (C), 0, 0, 0)

__global__ __launch_bounds__(512, 1) void lstm2_fused(
    const float* __restrict__ x,   // [B][S][I]
    const float* __restrict__ W0,  // [4H][I+H]
    const float* __restrict__ b0,  // [4H]
    const float* __restrict__ W1,  // [4H][2H]
    const float* __restrict__ b1,  // [4H]
    float* __restrict__ out,       // [B][S][H] then h[2][B][H], c[2][B][H]
    int* flags,                    // [NBLK*32]: block b's counter at flags[b*32]
    __bf16* h0buf, __bf16* h1buf)  // [2][B][H] parity double buffers
{
    const int tid  = threadIdx.x;
    const int w    = tid >> 6;   // wave 0..7
    const int l    = tid & 63;
    const int cc   = l & 15;     // B-frag col (gate unit) / A-frag row (batch)
    const int kg   = l >> 4;     // k-group 0..3
    const int gate = w & 3;
    const bool isL0 = (w < 4);
    const int blk   = blockIdx.x;
    const int ubase = blk * 16;
    const int gcol  = gate * HH + ubase + cc;

    const int half = tid >> 8;   // 0: layer0 cell update, 1: layer1
    const int eb   = (tid >> 4) & 15;
    const int eu   = tid & 15;

    __shared__ float g0s[4][16][17];
    __shared__ float g1s[4][16][17];

    bf16x8_t wf[32];
    float    bias;
    bf16x8_t xf[8];
    const float* xrow = x + (size_t)cc * SS * II;  // batch cc

    if (isL0) {
        const float* wrow = W0 + (size_t)gcol * (II + HH);
#pragma unroll
        for (int kk = 0; kk < 24; ++kk)
            wf[kk] = cvt8(wrow + kk * 32 + kg * 8);
        bias = b0[gcol];
#pragma unroll
        for (int kk = 0; kk < 8; ++kk)                 // x[0] prologue
            xf[kk] = cvt8(xrow + kk * 32 + kg * 8);
    } else {
        const float* wrow = W1 + (size_t)gcol * (2 * HH);
#pragma unroll
        for (int kk = 0; kk < 32; ++kk)
            wf[kk] = cvt8(wrow + kk * 32 + kg * 8);
        bias = b1[gcol];
    }

    float cstate = 0.f;
    __syncthreads();

    for (int t = 0; t <= SS; ++t) {
        f32x4_t a0 = {0.f, 0.f, 0.f, 0.f}, a1 = a0, a2 = a0, a3 = a0;
        f32x4_t xraw[16];

        if (isL0 && t < SS) {
            // x-part MFMAs: independent of peers — before the handshake
            a0 = MFMA(xf[0], wf[0], a0); a1 = MFMA(xf[1], wf[1], a1);
            a2 = MFMA(xf[2], wf[2], a2); a3 = MFMA(xf[3], wf[3], a3);
            a0 = MFMA(xf[4], wf[4], a0); a1 = MFMA(xf[5], wf[5], a1);
            a2 = MFMA(xf[6], wf[6], a2); a3 = MFMA(xf[7], wf[7], a3);
            if (t + 1 < SS) {
                // next-step x loads; latency hides under the spin
                const float* xr = xrow + (size_t)(t + 1) * II;
#pragma unroll
                for (int kk = 0; kk < 8; ++kk) {
                    xraw[2 * kk]     = *reinterpret_cast<const f32x4_t*>(xr + kk * 32 + kg * 8);
                    xraw[2 * kk + 1] = *reinterpret_cast<const f32x4_t*>(xr + kk * 32 + kg * 8 + 4);
                }
            }
        }

        // ---- single grid handshake: all blocks completed superstep t-1
        if (w == 0) {
            const int* p = flags + (l & 31) * 32;   // one 128-B line per block
            while (true) {
                int v = __hip_atomic_load(p, __ATOMIC_RELAXED, __HIP_MEMORY_SCOPE_AGENT);
                if (__all(v >= t)) break;
            }
        }
        __syncthreads();

        if (isL0) {
            if (t < SS) {
                if (t + 1 < SS) {  // pack next x first: kill xraw live range
#pragma unroll
                    for (int kk = 0; kk < 8; ++kk)
                        xf[kk] = pack8(xraw[2 * kk], xraw[2 * kk + 1]);
                }
                if (t > 0) {
                    const __bf16* hp = h0buf + ((t - 1) & 1) * BHH + cc * HH + kg * 8;
                    bf16x8_t hf[16];
                    cload_block16(hf, hp);   // 16 loads in flight
                    WAIT_VMEM();             // ONE latency for all
#pragma unroll
                    for (int kk = 0; kk < 16; kk += 4) {
                        a0 = MFMA(hf[kk + 0], wf[8 + kk + 0], a0);
                        a1 = MFMA(hf[kk + 1], wf[8 + kk + 1], a1);
                        a2 = MFMA(hf[kk + 2], wf[8 + kk + 2], a2);
                        a3 = MFMA(hf[kk + 3], wf[8 + kk + 3], a3);
                    }
                }
                f32x4_t acc = (a0 + a1) + (a2 + a3);
#pragma unroll
                for (int r = 0; r < 4; ++r)
                    g0s[gate][cc][kg * 4 + r] = acc[r] + bias;
            }
        } else {
            if (t >= 1) {
                {   // h0[t-1] chunk (wf[0..15])
                    const __bf16* h0c = h0buf + ((t - 1) & 1) * BHH + cc * HH + kg * 8;
                    bf16x8_t hf[16];
                    cload_block16(hf, h0c);
                    WAIT_VMEM();
#pragma unroll
                    for (int kk = 0; kk < 16; kk += 4) {
                        a0 = MFMA(hf[kk + 0], wf[kk + 0], a0);
                        a1 = MFMA(hf[kk + 1], wf[kk + 1], a1);
                        a2 = MFMA(hf[kk + 2], wf[kk + 2], a2);
                        a3 = MFMA(hf[kk + 3], wf[kk + 3], a3);
                    }
                }
                if (t >= 2) {  // h1[t-2] chunk (wf[16..31])
                    const __bf16* h1p = h1buf + ((t - 2) & 1) * BHH + cc * HH + kg * 8;
                    bf16x8_t hf[16];
                    cload_block16(hf, h1p);
                    WAIT_VMEM();
#pragma unroll
                    for (int kk = 0; kk < 16; kk += 4) {
                        a0 = MFMA(hf[kk + 0], wf[16 + kk + 0], a0);
                        a1 = MFMA(hf[kk + 1], wf[16 + kk + 1], a1);
                        a2 = MFMA(hf[kk + 2], wf[16 + kk + 2], a2);
                        a3 = MFMA(hf[kk + 3], wf[16 + kk + 3], a3);
                    }
                }
                f32x4_t acc = (a0 + a1) + (a2 + a3);
#pragma unroll
                for (int r = 0; r < 4; ++r)
                    g1s[gate][cc][kg * 4 + r] = acc[r] + bias;
            }
        }
        __syncthreads();

        if (half == 0) {
            if (t < SS) {
                const float gi = g0s[0][eu][eb];
                const float gf = g0s[1][eu][eb];
                const float gg = g0s[2][eu][eb];
                const float go = g0s[3][eu][eb];
                const float cn = sigmoidf_(gf) * cstate + sigmoidf_(gi) * tanhf_(gg);
                const float hn = sigmoidf_(go) * tanhf_(cn);
                cstate = cn;
                cstore_bf16(h0buf + (t & 1) * BHH + eb * HH + ubase + eu, hn);
                if (t == SS - 1) {
                    out[OUT_H_OFF + eb * HH + ubase + eu] = hn;
                    out[OUT_C_OFF + eb * HH + ubase + eu] = cn;
                }
            }
        } else {
            if (t >= 1) {
                const float gi = g1s[0][eu][eb];
                const float gf = g1s[1][eu][eb];
                const float gg = g1s[2][eu][eb];
                const float go = g1s[3][eu][eb];
                const float cn = sigmoidf_(gf) * cstate + sigmoidf_(gi) * tanhf_(gg);
                const float hn = sigmoidf_(go) * tanhf_(cn);
                cstate = cn;
                cstore_bf16(h1buf + ((t - 1) & 1) * BHH + eb * HH + ubase + eu, hn);
                out[((size_t)eb * SS + (t - 1)) * HH + ubase + eu] = hn;
                if (t == SS) {
                    out[OUT_H_OFF + (BB + eb) * HH + ubase + eu] = hn;
                    out[OUT_C_OFF + (BB + eb) * HH + ubase + eu] = cn;
                }
            }
        }

        asm volatile("s_waitcnt vmcnt(0)" ::: "memory");  // h stores at LLC
        __syncthreads();                                  // all waves drained
        if (tid == 0)
            __hip_atomic_store(flags + blk * 32, t + 1, __ATOMIC_RELAXED,
                               __HIP_MEMORY_SCOPE_AGENT);
    }
}

extern "C" void kernel_launch(void* const* d_in, const int* in_sizes, int n_in,
                              void* d_out, int out_size, void* d_ws, size_t ws_size,
                              hipStream_t stream) {
    const float* x  = (const float*)d_in[0];
    const float* W0 = (const float*)d_in[1];
    const float* b0 = (const float*)d_in[2];
    const float* W1 = (const float*)d_in[3];
    const float* b1 = (const float*)d_in[4];
    float* out = (float*)d_out;

    char* ws = (char*)d_ws;
    int* flags = (int*)ws;                          // NBLK * 32 ints (padded)
    __bf16* h0buf = (__bf16*)(ws + 8192);           // 2*B*H bf16 = 32 KB
    __bf16* h1buf = (__bf16*)(ws + 8192 + 32768);   // 2*B*H bf16 = 32 KB

    hipMemsetAsync(ws, 0, 8192, stream);  // zero flag counters

    hipLaunchKernelGGL(lstm2_fused, dim3(NBLK), dim3(512), 0, stream,
                       x, W0, b0, W1, b1, out, flags, h0buf, h1buf);
}